// Round 6
// baseline (178.091 us; speedup 1.0000x reference)
//
#include <hip/hip_runtime.h>
#include <cstdint>
#include <cstddef>

#define B_   8
#define S_   1024
#define H_   1024
#define NH_  16
#define HD_  64
#define M_   8192   // B*S
#define N3_  3072   // 3*H
#define K_   1024

typedef __attribute__((ext_vector_type(8))) short bf16x8;
typedef __attribute__((ext_vector_type(4))) float f32x4;
typedef __attribute__((ext_vector_type(16))) float f32x16;
typedef __attribute__((ext_vector_type(8))) unsigned short u16x8;
typedef __attribute__((ext_vector_type(4))) unsigned u32x4;

__device__ __forceinline__ unsigned short f2bf(float f) {
  unsigned u = __builtin_bit_cast(unsigned, f);
  u += 0x7fffu + ((u >> 16) & 1u);      // round-to-nearest-even (finite inputs)
  return (unsigned short)(u >> 16);
}

// one-instruction bf16-pair pack (RNE), T12 recipe
__device__ __forceinline__ unsigned cvtpk(float a, float b) {
  unsigned r;
  asm("v_cvt_pk_bf16_f32 %0, %1, %2" : "=v"(r) : "v"(a), "v"(b));
  return r;
}

// ---------------- fp32 -> bf16 pack ----------------
__global__ void cvt_kernel(const float* __restrict__ src,
                           unsigned short* __restrict__ dst, int n) {
  const int stride = gridDim.x * blockDim.x * 8;
  for (int i = (blockIdx.x * blockDim.x + threadIdx.x) * 8; i < n; i += stride) {
    float4 a = *reinterpret_cast<const float4*>(src + i);
    float4 b = *reinterpret_cast<const float4*>(src + i + 4);
    u16x8 o;
    o[0] = f2bf(a.x); o[1] = f2bf(a.y); o[2] = f2bf(a.z); o[3] = f2bf(a.w);
    o[4] = f2bf(b.x); o[5] = f2bf(b.y); o[6] = f2bf(b.z); o[7] = f2bf(b.w);
    *reinterpret_cast<u16x8*>(dst + i) = o;
  }
}

// ---------------- fused QKV GEMM: 256x256 tile, 8-phase pipelined ----------------
// 512 thr = 8 waves (2 wm x 4 wn). Per-wave 128x64 as two 64-row strips
// (rows mh*128+wm*64) x two 32-col strips (cols nh*128+wn*32). Phase (mh,nh)
// reads exactly staged A-half mh + B-half nh -> half-tiles retire early.
// Counted vmcnt(4) (never 0 in loop); raw s_barrier (no drain); T5 setprio.
__global__ __launch_bounds__(512, 2) void qkv_gemm(
    const unsigned short* __restrict__ A,    // [8192][1024] bf16
    const unsigned short* __restrict__ Bw,   // [3072][1024] bf16 (qw|kw|vw rows)
    const float* __restrict__ qb, const float* __restrict__ kb,
    const float* __restrict__ vb,
    unsigned short* __restrict__ Qh,   // [128][1024][64], pre-scaled by log2e/32
    unsigned short* __restrict__ Kh,   // [128][1024][64]
    unsigned short* __restrict__ Vth)  // [128][16 kt][64 hd][64 k]
{
  extern __shared__ char sm[];            // 128 KiB: A[2][32K] | B[2][32K]
  char* Asm = sm;
  char* Bsm = sm + 65536;

  const int t = threadIdx.x;
  const int lane = t & 63;
  const int wave = t >> 6;
  const int wm = wave >> 2;               // 0..1
  const int wn = wave & 3;                // 0..3

  // XCD swizzle: 384 blocks = 8 XCD x 48; bm-fast within an XCD chunk.
  const int bid = blockIdx.x;
  const int swz = (bid & 7) * 48 + (bid >> 3);
  const int bm = swz & 31;                // 0..31
  const int bn = swz >> 5;                // 0..11

  const char* Ab = (const char*)A + (size_t)bm * 256 * 2048;
  const char* Bb = (const char*)Bw + (size_t)bn * 256 * 2048;

  f32x4 acc[2][2][4][2] = {};   // [mh][nh][f][g]

  // stage one half-tile (16KB, rows [h*128,h*128+128)) of K-tile kt
  #define STG(lbase, gbase, kt, h)                                             \
    { _Pragma("unroll")                                                        \
      for (int j = 0; j < 2; ++j) {                                            \
        const int off = (h) * 16384 + j * 8192 + t * 16;                       \
        const int row = off >> 7;                                              \
        const int sc  = ((off >> 4) & 7) ^ (row & 7);                          \
        __builtin_amdgcn_global_load_lds(                                      \
          (const __attribute__((address_space(1))) void*)((gbase) + row * 2048 + (kt) * 128 + sc * 16), \
          (__attribute__((address_space(3))) void*)((lbase) + off), 16, 0, 0); \
      } }

  #define VM4 asm volatile("s_waitcnt vmcnt(4)" ::: "memory")
  #define VM2 asm volatile("s_waitcnt vmcnt(2)" ::: "memory")
  #define VM0 asm volatile("s_waitcnt vmcnt(0)" ::: "memory")
  #define BAR asm volatile("s_barrier" ::: "memory")
  #define NOPS

  // phase: ds_read 12 x b128 | stage | counted wait | barrier | 16 MFMA | barrier
  #define PHASE(MH, NH, STAGE_STMT, WAIT_STMT)                                 \
  {                                                                            \
    bf16x8 afr[2][4], bfr[2][2];                                               \
    _Pragma("unroll")                                                          \
    for (int ks = 0; ks < 2; ++ks) {                                           \
      _Pragma("unroll")                                                        \
      for (int f = 0; f < 4; ++f) {                                            \
        const int ar = (MH) * 128 + wm * 64 + f * 16 + (lane & 15);            \
        afr[ks][f] = *(const bf16x8*)(Acur + ar * 128 +                        \
                      (((ks * 4 + (lane >> 4)) ^ (ar & 7)) << 4));             \
      }                                                                        \
      _Pragma("unroll")                                                        \
      for (int g = 0; g < 2; ++g) {                                            \
        const int br = (NH) * 128 + wn * 32 + g * 16 + (lane & 15);            \
        bfr[ks][g] = *(const bf16x8*)(Bcur + br * 128 +                        \
                      (((ks * 4 + (lane >> 4)) ^ (br & 7)) << 4));             \
      }                                                                        \
    }                                                                          \
    STAGE_STMT;                                                                \
    WAIT_STMT;                                                                 \
    BAR;                                                                       \
    __builtin_amdgcn_s_setprio(1);                                             \
    _Pragma("unroll")                                                          \
    for (int ks = 0; ks < 2; ++ks)                                             \
      _Pragma("unroll")                                                        \
      for (int f = 0; f < 4; ++f)                                              \
        _Pragma("unroll")                                                      \
        for (int g = 0; g < 2; ++g)                                            \
          acc[MH][NH][f][g] = __builtin_amdgcn_mfma_f32_16x16x32_bf16(         \
              afr[ks][f], bfr[ks][g], acc[MH][NH][f][g], 0, 0, 0);             \
    __builtin_amdgcn_s_setprio(0);                                             \
    BAR;                                                                       \
  }

  // prologue: stage K-tile 0 in first-read order, confirm first 2 half-tiles
  STG(Asm, Ab, 0, 0)
  STG(Bsm, Bb, 0, 0)
  STG(Bsm, Bb, 0, 1)
  STG(Asm, Ab, 0, 1)
  VM4;
  BAR;

  for (int kt = 0; kt < 15; ++kt) {
    const char* Acur = Asm + (kt & 1) * 32768;
    const char* Bcur = Bsm + (kt & 1) * 32768;
    char* Anx = Asm + ((kt + 1) & 1) * 32768;
    char* Bnx = Bsm + ((kt + 1) & 1) * 32768;
    PHASE(0, 0, STG(Anx, Ab, kt + 1, 0), VM4)
    PHASE(0, 1, STG(Bnx, Bb, kt + 1, 0), VM4)
    PHASE(1, 0, STG(Bnx, Bb, kt + 1, 1), NOPS)
    PHASE(1, 1, STG(Anx, Ab, kt + 1, 1), VM4)
  }
  {  // last K-tile: no staging; drain 4->2->0 (counted until the very end)
    const char* Acur = Asm + 32768;
    const char* Bcur = Bsm + 32768;
    PHASE(0, 0, NOPS, VM2)
    PHASE(0, 1, NOPS, VM0)
    PHASE(1, 0, NOPS, NOPS)
    PHASE(1, 1, NOPS, NOPS)
  }

  // epilogue: bias, Q scale log2e/32, head-major scatter (V kt-tiled transpose)
  #pragma unroll
  for (int mh = 0; mh < 2; ++mh) {
    #pragma unroll
    for (int nh = 0; nh < 2; ++nh) {
      #pragma unroll
      for (int g = 0; g < 2; ++g) {
        const int col = bn * 256 + nh * 128 + wn * 32 + g * 16 + (lane & 15);
        const int tensor = col >> 10;
        const int o  = col & 1023;
        const int nhh = o >> 6, hd = o & 63;
        const float* bias = (tensor == 0) ? qb : (tensor == 1) ? kb : vb;
        const float bv  = bias[o];
        const float scl = (tensor == 0) ? 0.04508422f : 1.0f;  // log2e/sqrt(1024)
        #pragma unroll
        for (int f = 0; f < 4; ++f) {
          #pragma unroll
          for (int r = 0; r < 4; ++r) {
            const int i = bm * 256 + mh * 128 + wm * 64 + f * 16 + (lane >> 4) * 4 + r;
            const int bb = i >> 10, s = i & 1023;
            const unsigned short hval = f2bf((acc[mh][nh][f][g][r] + bv) * scl);
            const int bhn = bb * NH_ + nhh;
            if (tensor == 0)      Qh[((size_t)bhn * S_ + s) * HD_ + hd] = hval;
            else if (tensor == 1) Kh[((size_t)bhn * S_ + s) * HD_ + hd] = hval;
            else                  Vth[(size_t)bhn * 65536 + (s >> 6) * 4096 + hd * 64 + (s & 63)] = hval;
          }
        }
      }
    }
  }
}

// ---- build PV A-frag for one 16-k step from 8 consecutive P regs ----
__device__ __forceinline__ bf16x8 mk_frag(const f32x16& s, const int base) {
  unsigned a0 = cvtpk(s[base + 0], s[base + 1]);
  unsigned a1 = cvtpk(s[base + 2], s[base + 3]);
  unsigned b0 = cvtpk(s[base + 4], s[base + 5]);
  unsigned b1 = cvtpk(s[base + 6], s[base + 7]);
  asm("v_permlane32_swap_b32 %0, %1" : "+v"(a0), "+v"(b0));
  asm("v_permlane32_swap_b32 %0, %1" : "+v"(a1), "+v"(b1));
  u32x4 u = {a0, a1, b0, b1};
  return __builtin_bit_cast(bf16x8, u);
}

// ---------------- flash attention: LDS-staged K/V, double-buffered ----------------
__global__ __launch_bounds__(256, 3) void attn_kernel(
    const unsigned short* __restrict__ Qh,
    const unsigned short* __restrict__ Kh,
    const unsigned short* __restrict__ Vth,
    float* __restrict__ Out)
{
  __shared__ char smx[2][16384];   // [buf][ K 8KB | V 8KB ]
  const int t = threadIdx.x;
  const int lane = t & 63;
  const int wave = t >> 6;
  const int l31 = lane & 31;
  const int hi = lane >> 5;
  const int hw = blockIdx.x;              // 0..1023
  const int xcd = hw & 7;
  const int qt = (hw >> 3) & 7;
  const int bh = (hw >> 6) * 8 + xcd;     // 0..127
  const int b = bh >> 4, nh = bh & 15;

  const unsigned short* Qp = Qh + (size_t)bh * (S_ * HD_);
  const char* Kp = (const char*)Kh + (size_t)bh * 131072;
  const char* Vp = (const char*)Vth + (size_t)bh * 131072;
  const int q0 = qt * 128 + wave * 32;

  bf16x8 bq[4];
  #pragma unroll
  for (int st = 0; st < 4; ++st)
    bq[st] = *reinterpret_cast<const bf16x8*>(
        Qp + (size_t)(q0 + l31) * HD_ + st * 16 + hi * 8);

  const int soff0 = wave * 1024 + lane * 16;
  #define STAGE_TILE(dstbase, srcbase)                                            \
    _Pragma("unroll")                                                             \
    for (int j = 0; j < 2; ++j) {                                                 \
      const int off = j * 4096 + soff0;                                           \
      const int row = off >> 7;                                                   \
      const int sc  = ((off >> 4) & 7) ^ (row & 7);                               \
      __builtin_amdgcn_global_load_lds(                                           \
          (const __attribute__((address_space(1))) void*)((srcbase) + row * 128 + sc * 16), \
          (__attribute__((address_space(3))) void*)((dstbase) + off), 16, 0, 0);  \
    }

  STAGE_TILE(&smx[0][0],    Kp)
  STAGE_TILE(&smx[0][8192], Vp)
  __syncthreads();

  f32x16 o0 = {}, o1 = {};
  float lsum = 0.f;
  const int swr = l31 & 7;

  for (int kt = 0; kt < 16; ++kt) {
    const int cur = kt & 1;
    if (kt < 15) {
      STAGE_TILE(&smx[cur ^ 1][0],    Kp + (kt + 1) * 8192)
      STAGE_TILE(&smx[cur ^ 1][8192], Vp + (kt + 1) * 8192)
    }
    const char* Kb = &smx[cur][0];
    const char* Vb = &smx[cur][8192];

    f32x16 s0 = {}, s1 = {};
    #pragma unroll
    for (int st = 0; st < 4; ++st) {
      const int c = ((st * 2 + hi) ^ swr) << 4;
      bf16x8 ka = *reinterpret_cast<const bf16x8*>(Kb + l31 * 128 + c);
      bf16x8 kc = *reinterpret_cast<const bf16x8*>(Kb + (l31 + 32) * 128 + c);
      s0 = __builtin_amdgcn_mfma_f32_32x32x16_bf16(ka, bq[st], s0, 0, 0, 0);
      s1 = __builtin_amdgcn_mfma_f32_32x32x16_bf16(kc, bq[st], s1, 0, 0, 0);
    }

    bf16x8 va[4];
    #pragma unroll
    for (int ks = 0; ks < 2; ++ks) {
      const int c = ((ks * 2 + hi) ^ swr) << 4;
      va[ks * 2]     = *reinterpret_cast<const bf16x8*>(Vb + l31 * 128 + c);
      va[ks * 2 + 1] = *reinterpret_cast<const bf16x8*>(Vb + (l31 + 32) * 128 + c);
    }
    #pragma unroll
    for (int r = 0; r < 16; ++r) {
      s0[r] = __builtin_amdgcn_exp2f(s0[r]);
      lsum += s0[r];
    }
    bf16x8 f0 = mk_frag(s0, 0);
    bf16x8 f1 = mk_frag(s0, 8);
    o0 = __builtin_amdgcn_mfma_f32_32x32x16_bf16(f0, va[0], o0, 0, 0, 0);
    o1 = __builtin_amdgcn_mfma_f32_32x32x16_bf16(f0, va[1], o1, 0, 0, 0);
    o0 = __builtin_amdgcn_mfma_f32_32x32x16_bf16(f1, va[2], o0, 0, 0, 0);
    o1 = __builtin_amdgcn_mfma_f32_32x32x16_bf16(f1, va[3], o1, 0, 0, 0);

    #pragma unroll
    for (int ks = 0; ks < 2; ++ks) {
      const int c = (((ks + 2) * 2 + hi) ^ swr) << 4;
      va[ks * 2]     = *reinterpret_cast<const bf16x8*>(Vb + l31 * 128 + c);
      va[ks * 2 + 1] = *reinterpret_cast<const bf16x8*>(Vb + (l31 + 32) * 128 + c);
    }
    #pragma unroll
    for (int r = 0; r < 16; ++r) {
      s1[r] = __builtin_amdgcn_exp2f(s1[r]);
      lsum += s1[r];
    }
    bf16x8 f2 = mk_frag(s1, 0);
    bf16x8 f3 = mk_frag(s1, 8);
    o0 = __builtin_amdgcn_mfma_f32_32x32x16_bf16(f2, va[0], o0, 0, 0, 0);
    o1 = __builtin_amdgcn_mfma_f32_32x32x16_bf16(f2, va[1], o1, 0, 0, 0);
    o0 = __builtin_amdgcn_mfma_f32_32x32x16_bf16(f3, va[2], o0, 0, 0, 0);
    o1 = __builtin_amdgcn_mfma_f32_32x32x16_bf16(f3, va[3], o1, 0, 0, 0);

    __syncthreads();
  }

  const float ltot = lsum + __shfl_xor(lsum, 32);
  const float inv = 1.0f / ltot;
  #pragma unroll
  for (int r = 0; r < 16; ++r) {
    const int crow = (r & 3) + 8 * (r >> 2) + 4 * hi;
    const float invq = __shfl(inv, crow);
    float* op = Out + ((size_t)(b * S_ + q0 + crow)) * H_ + nh * HD_ + l31;
    op[0]  = o0[r] * invq;
    op[32] = o1[r] * invq;
  }
}

extern "C" void kernel_launch(void* const* d_in, const int* in_sizes, int n_in,
                              void* d_out, int out_size, void* d_ws, size_t ws_size,
                              hipStream_t stream) {
  const float* act = (const float*)d_in[0];
  const float* qw  = (const float*)d_in[1];
  const float* qb  = (const float*)d_in[2];
  const float* kw  = (const float*)d_in[3];
  const float* kb  = (const float*)d_in[4];
  const float* vw  = (const float*)d_in[5];
  const float* vb  = (const float*)d_in[6];

  char* ws = (char*)d_ws;
  unsigned short* actb = (unsigned short*)ws;                         // 16 MB
  unsigned short* wb   = (unsigned short*)(ws + 16777216);            // 6 MB
  unsigned short* Qh   = (unsigned short*)(ws + 23068672);            // 16 MB
  unsigned short* Kh   = Qh + 8388608;                                // 16 MB
  unsigned short* Vth  = Kh + 8388608;                                // 16 MB

  cvt_kernel<<<4096, 256, 0, stream>>>(act, actb, M_ * K_);
  cvt_kernel<<<512, 256, 0, stream>>>(qw, wb,               H_ * H_);
  cvt_kernel<<<512, 256, 0, stream>>>(kw, wb + 1048576,     H_ * H_);
  cvt_kernel<<<512, 256, 0, stream>>>(vw, wb + 2097152,     H_ * H_);

  hipFuncSetAttribute((const void*)qkv_gemm,
                      hipFuncAttributeMaxDynamicSharedMemorySize, 131072);
  qkv_gemm<<<384, 512, 131072, stream>>>(actb, wb, qb, kb, vb, Qh, Kh, Vth);

  attn_kernel<<<1024, 256, 0, stream>>>(Qh, Kh, Vth, (float*)d_out);
}

// Round 7
// 145.356 us; speedup vs baseline: 1.2252x; 1.2252x over previous
//
#include <hip/hip_runtime.h>
#include <cstdint>
#include <cstddef>

#define B_   8
#define S_   1024
#define H_   1024
#define NH_  16
#define HD_  64
#define M_   8192   // B*S
#define N3_  3072   // 3*H
#define K_   1024

typedef __attribute__((ext_vector_type(8))) short bf16x8;
typedef __attribute__((ext_vector_type(4))) float f32x4;
typedef __attribute__((ext_vector_type(16))) float f32x16;
typedef __attribute__((ext_vector_type(8))) unsigned short u16x8;
typedef __attribute__((ext_vector_type(4))) unsigned u32x4;

__device__ __forceinline__ unsigned short f2bf(float f) {
  unsigned u = __builtin_bit_cast(unsigned, f);
  u += 0x7fffu + ((u >> 16) & 1u);      // round-to-nearest-even (finite inputs)
  return (unsigned short)(u >> 16);
}

// one-instruction bf16-pair pack (RNE), T12 recipe
__device__ __forceinline__ unsigned cvtpk(float a, float b) {
  unsigned r;
  asm("v_cvt_pk_bf16_f32 %0, %1, %2" : "=v"(r) : "v"(a), "v"(b));
  return r;
}

// ---------------- fp32 -> bf16 pack ----------------
__global__ void cvt_kernel(const float* __restrict__ src,
                           unsigned short* __restrict__ dst, int n) {
  const int stride = gridDim.x * blockDim.x * 8;
  for (int i = (blockIdx.x * blockDim.x + threadIdx.x) * 8; i < n; i += stride) {
    float4 a = *reinterpret_cast<const float4*>(src + i);
    float4 b = *reinterpret_cast<const float4*>(src + i + 4);
    u16x8 o;
    o[0] = f2bf(a.x); o[1] = f2bf(a.y); o[2] = f2bf(a.z); o[3] = f2bf(a.w);
    o[4] = f2bf(b.x); o[5] = f2bf(b.y); o[6] = f2bf(b.z); o[7] = f2bf(b.w);
    *reinterpret_cast<u16x8*>(dst + i) = o;
  }
}

// ---------------- fused QKV GEMM: 256x256, 4-phase/K-tile, deep stage ring ----
// 512 thr = 8 waves (2 wm x 4 wn), per-wave 128x64. Phases (mh,nh) quadrants,
// frags kept in regs: reads/K-tile = 12,4,8,0 ds_read_b128. Stage ring: P1/P2
// stage {B1,A1}(k+1), P3/P4 stage {A0,B0}(k+2); ONE vmcnt(4) per K-tile at P4
// (12-deep in flight). One barrier per phase (after stage+wait, before MFMA).
__global__ __launch_bounds__(512, 1) void qkv_gemm(
    const unsigned short* __restrict__ A,    // [8192][1024] bf16
    const unsigned short* __restrict__ Bw,   // [3072][1024] bf16 (qw|kw|vw rows)
    const float* __restrict__ qb, const float* __restrict__ kb,
    const float* __restrict__ vb,
    unsigned short* __restrict__ Qh,   // [128][1024][64], pre-scaled by log2e/32
    unsigned short* __restrict__ Kh,   // [128][1024][64]
    unsigned short* __restrict__ Vth)  // [128][16 kt][64 hd][64 k]
{
  extern __shared__ char sm[];            // 128 KiB: A[2][32K] | B[2][32K]
  char* Asm = sm;
  char* Bsm = sm + 65536;

  const int t = threadIdx.x;
  const int lane = t & 63;
  const int wave = t >> 6;
  const int wm = wave >> 2;               // 0..1
  const int wn = wave & 3;                // 0..3

  // XCD chunking: xcd = bid&7 gets 4 consecutive bm x all 12 bn ->
  // per-XCD A window = 2MB (L2-resident), B via L3.
  const int bid = blockIdx.x;
  const int c = bid >> 3;                 // 0..47
  const int bm = (bid & 7) * 4 + c / 12;  // 0..31
  const int bn = c % 12;                  // 0..11

  const char* Ab = (const char*)A + (size_t)bm * 256 * 2048;
  const char* Bb = (const char*)Bw + (size_t)bn * 256 * 2048;

  f32x4 acc[2][2][4][2] = {};   // [mh][nh][f][g]

  // stage half-tile h (rows [h*128,h*128+128)) of K-slice kt into lbase+h*16K
  #define STG(lbase, gbase, kt, h)                                             \
    { _Pragma("unroll")                                                        \
      for (int j = 0; j < 2; ++j) {                                            \
        const int off = (h) * 16384 + j * 8192 + t * 16;                       \
        const int row = off >> 7;                                              \
        const int sc  = ((off >> 4) & 7) ^ (row & 7);                          \
        __builtin_amdgcn_global_load_lds(                                      \
          (const __attribute__((address_space(1))) void*)((gbase) + row * 2048 + (kt) * 128 + sc * 16), \
          (__attribute__((address_space(3))) void*)((lbase) + off), 16, 0, 0); \
      } }

  #define VM4 asm volatile("s_waitcnt vmcnt(4)" ::: "memory")
  #define VM0 asm volatile("s_waitcnt vmcnt(0)" ::: "memory")

  bf16x8 afr[2][4], bfr0[2][2], bfr1[2][2];

  #define READ_A(MH)                                                           \
    _Pragma("unroll")                                                          \
    for (int ks = 0; ks < 2; ++ks)                                             \
      _Pragma("unroll")                                                        \
      for (int f = 0; f < 4; ++f) {                                            \
        const int ar = (MH) * 128 + wm * 64 + f * 16 + (lane & 15);            \
        afr[ks][f] = *(const bf16x8*)(Acur + ar * 128 +                        \
                      (((ks * 4 + (lane >> 4)) ^ (ar & 7)) << 4));             \
      }

  #define READ_B(DST, NH)                                                     \
    _Pragma("unroll")                                                          \
    for (int ks = 0; ks < 2; ++ks)                                             \
      _Pragma("unroll")                                                        \
      for (int g = 0; g < 2; ++g) {                                            \
        const int br = (NH) * 128 + wn * 32 + g * 16 + (lane & 15);            \
        DST[ks][g] = *(const bf16x8*)(Bcur + br * 128 +                        \
                      (((ks * 4 + (lane >> 4)) ^ (br & 7)) << 4));             \
      }

  #define MFMA16(MH, NH, BF)                                                   \
    __builtin_amdgcn_s_setprio(1);                                             \
    _Pragma("unroll")                                                          \
    for (int ks = 0; ks < 2; ++ks)                                             \
      _Pragma("unroll")                                                        \
      for (int f = 0; f < 4; ++f)                                              \
        _Pragma("unroll")                                                      \
        for (int g = 0; g < 2; ++g)                                            \
          acc[MH][NH][f][g] = __builtin_amdgcn_mfma_f32_16x16x32_bf16(         \
              afr[ks][f], BF[ks][g], acc[MH][NH][f][g], 0, 0, 0);              \
    __builtin_amdgcn_s_setprio(0);

  // prologue: k0 fully + {A0,B0}(k1); VM4 confirms k0, leaves 4 in flight
  STG(Asm, Ab, 0, 0)
  STG(Bsm, Bb, 0, 0)
  STG(Bsm, Bb, 0, 1)
  STG(Asm, Ab, 0, 1)
  STG(Asm + 32768, Ab, 1, 0)
  STG(Bsm + 32768, Bb, 1, 0)
  VM4;
  __builtin_amdgcn_s_barrier();

  for (int kt = 0; kt < 14; ++kt) {
    const char* Acur = Asm + (kt & 1) * 32768;
    const char* Bcur = Bsm + (kt & 1) * 32768;
    char* An = Asm + ((kt + 1) & 1) * 32768;
    char* Bn = Bsm + ((kt + 1) & 1) * 32768;
    char* Ac2 = Asm + (kt & 1) * 32768;       // k+2 shares cur buffer
    char* Bc2 = Bsm + (kt & 1) * 32768;
    // P1 (0,0)
    READ_A(0) READ_B(bfr0, 0)
    STG(Bn, Bb, kt + 1, 1)
    __builtin_amdgcn_s_barrier();
    MFMA16(0, 0, bfr0)
    // P2 (0,1): reuse afr
    READ_B(bfr1, 1)
    STG(An, Ab, kt + 1, 1)
    __builtin_amdgcn_s_barrier();
    MFMA16(0, 1, bfr1)
    // P3 (1,0): reuse bfr0
    READ_A(1)
    STG(Ac2, Ab, kt + 2, 0)
    __builtin_amdgcn_s_barrier();
    MFMA16(1, 0, bfr0)
    // P4 (1,1): reuse afr + bfr1; single counted wait per K-tile
    STG(Bc2, Bb, kt + 2, 0)
    VM4;
    __builtin_amdgcn_s_barrier();
    MFMA16(1, 1, bfr1)
  }
  {  // kt = 14: stage only {B1,A1}(15); drain fully at P4
    const char* Acur = Asm;
    const char* Bcur = Bsm;
    char* An = Asm + 32768; char* Bn = Bsm + 32768;
    READ_A(0) READ_B(bfr0, 0)
    STG(Bn, Bb, 15, 1)
    __builtin_amdgcn_s_barrier();
    MFMA16(0, 0, bfr0)
    READ_B(bfr1, 1)
    STG(An, Ab, 15, 1)
    __builtin_amdgcn_s_barrier();
    MFMA16(0, 1, bfr1)
    READ_A(1)
    __builtin_amdgcn_s_barrier();
    MFMA16(1, 0, bfr0)
    VM0;
    __builtin_amdgcn_s_barrier();
    MFMA16(1, 1, bfr1)
  }
  {  // kt = 15: pure compute
    const char* Acur = Asm + 32768;
    const char* Bcur = Bsm + 32768;
    READ_A(0) READ_B(bfr0, 0)
    MFMA16(0, 0, bfr0)
    READ_B(bfr1, 1)
    MFMA16(0, 1, bfr1)
    READ_A(1)
    MFMA16(1, 0, bfr0)
    MFMA16(1, 1, bfr1)
  }

  // epilogue: bias, Q scale log2e/32, head-major scatter (V kt-tiled transpose)
  #pragma unroll
  for (int mh = 0; mh < 2; ++mh) {
    #pragma unroll
    for (int nh = 0; nh < 2; ++nh) {
      #pragma unroll
      for (int g = 0; g < 2; ++g) {
        const int col = bn * 256 + nh * 128 + wn * 32 + g * 16 + (lane & 15);
        const int tensor = col >> 10;
        const int o  = col & 1023;
        const int nhh = o >> 6, hd = o & 63;
        const float* bias = (tensor == 0) ? qb : (tensor == 1) ? kb : vb;
        const float bv  = bias[o];
        const float scl = (tensor == 0) ? 0.04508422f : 1.0f;  // log2e/sqrt(1024)
        #pragma unroll
        for (int f = 0; f < 4; ++f) {
          #pragma unroll
          for (int r = 0; r < 4; ++r) {
            const int i = bm * 256 + mh * 128 + wm * 64 + f * 16 + (lane >> 4) * 4 + r;
            const int bb = i >> 10, s = i & 1023;
            const unsigned short hval = f2bf((acc[mh][nh][f][g][r] + bv) * scl);
            const int bhn = bb * NH_ + nhh;
            if (tensor == 0)      Qh[((size_t)bhn * S_ + s) * HD_ + hd] = hval;
            else if (tensor == 1) Kh[((size_t)bhn * S_ + s) * HD_ + hd] = hval;
            else                  Vth[(size_t)bhn * 65536 + (s >> 6) * 4096 + hd * 64 + (s & 63)] = hval;
          }
        }
      }
    }
  }
}

// ---- build PV A-frag for one 16-k step from 8 consecutive P regs ----
__device__ __forceinline__ bf16x8 mk_frag(const f32x16& s, const int base) {
  unsigned a0 = cvtpk(s[base + 0], s[base + 1]);
  unsigned a1 = cvtpk(s[base + 2], s[base + 3]);
  unsigned b0 = cvtpk(s[base + 4], s[base + 5]);
  unsigned b1 = cvtpk(s[base + 6], s[base + 7]);
  asm("v_permlane32_swap_b32 %0, %1" : "+v"(a0), "+v"(b0));
  asm("v_permlane32_swap_b32 %0, %1" : "+v"(a1), "+v"(b1));
  u32x4 u = {a0, a1, b0, b1};
  return __builtin_bit_cast(bf16x8, u);
}

// ---------------- flash attention: LDS-staged K/V, double-buffered ----------------
__global__ __launch_bounds__(256, 3) void attn_kernel(
    const unsigned short* __restrict__ Qh,
    const unsigned short* __restrict__ Kh,
    const unsigned short* __restrict__ Vth,
    float* __restrict__ Out)
{
  __shared__ char smx[2][16384];   // [buf][ K 8KB | V 8KB ]
  const int t = threadIdx.x;
  const int lane = t & 63;
  const int wave = t >> 6;
  const int l31 = lane & 31;
  const int hi = lane >> 5;
  const int hw = blockIdx.x;              // 0..1023
  const int xcd = hw & 7;
  const int qt = (hw >> 3) & 7;
  const int bh = (hw >> 6) * 8 + xcd;     // 0..127
  const int b = bh >> 4, nh = bh & 15;

  const unsigned short* Qp = Qh + (size_t)bh * (S_ * HD_);
  const char* Kp = (const char*)Kh + (size_t)bh * 131072;
  const char* Vp = (const char*)Vth + (size_t)bh * 131072;
  const int q0 = qt * 128 + wave * 32;

  bf16x8 bq[4];
  #pragma unroll
  for (int st = 0; st < 4; ++st)
    bq[st] = *reinterpret_cast<const bf16x8*>(
        Qp + (size_t)(q0 + l31) * HD_ + st * 16 + hi * 8);

  const int soff0 = wave * 1024 + lane * 16;
  #define STAGE_TILE(dstbase, srcbase)                                            \
    _Pragma("unroll")                                                             \
    for (int j = 0; j < 2; ++j) {                                                 \
      const int off = j * 4096 + soff0;                                           \
      const int row = off >> 7;                                                   \
      const int sc  = ((off >> 4) & 7) ^ (row & 7);                               \
      __builtin_amdgcn_global_load_lds(                                           \
          (const __attribute__((address_space(1))) void*)((srcbase) + row * 128 + sc * 16), \
          (__attribute__((address_space(3))) void*)((dstbase) + off), 16, 0, 0);  \
    }

  STAGE_TILE(&smx[0][0],    Kp)
  STAGE_TILE(&smx[0][8192], Vp)
  __syncthreads();

  f32x16 o0 = {}, o1 = {};
  float lsum = 0.f;
  const int swr = l31 & 7;

  for (int kt = 0; kt < 16; ++kt) {
    const int cur = kt & 1;
    if (kt < 15) {
      STAGE_TILE(&smx[cur ^ 1][0],    Kp + (kt + 1) * 8192)
      STAGE_TILE(&smx[cur ^ 1][8192], Vp + (kt + 1) * 8192)
    }
    const char* Kb = &smx[cur][0];
    const char* Vb = &smx[cur][8192];

    f32x16 s0 = {}, s1 = {};
    #pragma unroll
    for (int st = 0; st < 4; ++st) {
      const int c = ((st * 2 + hi) ^ swr) << 4;
      bf16x8 ka = *reinterpret_cast<const bf16x8*>(Kb + l31 * 128 + c);
      bf16x8 kc = *reinterpret_cast<const bf16x8*>(Kb + (l31 + 32) * 128 + c);
      s0 = __builtin_amdgcn_mfma_f32_32x32x16_bf16(ka, bq[st], s0, 0, 0, 0);
      s1 = __builtin_amdgcn_mfma_f32_32x32x16_bf16(kc, bq[st], s1, 0, 0, 0);
    }

    bf16x8 va[4];
    #pragma unroll
    for (int ks = 0; ks < 2; ++ks) {
      const int c = ((ks * 2 + hi) ^ swr) << 4;
      va[ks * 2]     = *reinterpret_cast<const bf16x8*>(Vb + l31 * 128 + c);
      va[ks * 2 + 1] = *reinterpret_cast<const bf16x8*>(Vb + (l31 + 32) * 128 + c);
    }
    #pragma unroll
    for (int r = 0; r < 16; ++r) {
      s0[r] = __builtin_amdgcn_exp2f(s0[r]);
      lsum += s0[r];
    }
    bf16x8 f0 = mk_frag(s0, 0);
    bf16x8 f1 = mk_frag(s0, 8);
    o0 = __builtin_amdgcn_mfma_f32_32x32x16_bf16(f0, va[0], o0, 0, 0, 0);
    o1 = __builtin_amdgcn_mfma_f32_32x32x16_bf16(f0, va[1], o1, 0, 0, 0);
    o0 = __builtin_amdgcn_mfma_f32_32x32x16_bf16(f1, va[2], o0, 0, 0, 0);
    o1 = __builtin_amdgcn_mfma_f32_32x32x16_bf16(f1, va[3], o1, 0, 0, 0);

    #pragma unroll
    for (int ks = 0; ks < 2; ++ks) {
      const int c = (((ks + 2) * 2 + hi) ^ swr) << 4;
      va[ks * 2]     = *reinterpret_cast<const bf16x8*>(Vb + l31 * 128 + c);
      va[ks * 2 + 1] = *reinterpret_cast<const bf16x8*>(Vb + (l31 + 32) * 128 + c);
    }
    #pragma unroll
    for (int r = 0; r < 16; ++r) {
      s1[r] = __builtin_amdgcn_exp2f(s1[r]);
      lsum += s1[r];
    }
    bf16x8 f2 = mk_frag(s1, 0);
    bf16x8 f3 = mk_frag(s1, 8);
    o0 = __builtin_amdgcn_mfma_f32_32x32x16_bf16(f2, va[0], o0, 0, 0, 0);
    o1 = __builtin_amdgcn_mfma_f32_32x32x16_bf16(f2, va[1], o1, 0, 0, 0);
    o0 = __builtin_amdgcn_mfma_f32_32x32x16_bf16(f3, va[2], o0, 0, 0, 0);
    o1 = __builtin_amdgcn_mfma_f32_32x32x16_bf16(f3, va[3], o1, 0, 0, 0);

    __syncthreads();
  }

  const float ltot = lsum + __shfl_xor(lsum, 32);
  const float inv = 1.0f / ltot;
  #pragma unroll
  for (int r = 0; r < 16; ++r) {
    const int crow = (r & 3) + 8 * (r >> 2) + 4 * hi;
    const float invq = __shfl(inv, crow);
    float* op = Out + ((size_t)(b * S_ + q0 + crow)) * H_ + nh * HD_ + l31;
    op[0]  = o0[r] * invq;
    op[32] = o1[r] * invq;
  }
}

extern "C" void kernel_launch(void* const* d_in, const int* in_sizes, int n_in,
                              void* d_out, int out_size, void* d_ws, size_t ws_size,
                              hipStream_t stream) {
  const float* act = (const float*)d_in[0];
  const float* qw  = (const float*)d_in[1];
  const float* qb  = (const float*)d_in[2];
  const float* kw  = (const float*)d_in[3];
  const float* kb  = (const float*)d_in[4];
  const float* vw  = (const float*)d_in[5];
  const float* vb  = (const float*)d_in[6];

  char* ws = (char*)d_ws;
  unsigned short* actb = (unsigned short*)ws;                         // 16 MB
  unsigned short* wb   = (unsigned short*)(ws + 16777216);            // 6 MB
  unsigned short* Qh   = (unsigned short*)(ws + 23068672);            // 16 MB
  unsigned short* Kh   = Qh + 8388608;                                // 16 MB
  unsigned short* Vth  = Kh + 8388608;                                // 16 MB

  cvt_kernel<<<4096, 256, 0, stream>>>(act, actb, M_ * K_);
  cvt_kernel<<<512, 256, 0, stream>>>(qw, wb,               H_ * H_);
  cvt_kernel<<<512, 256, 0, stream>>>(kw, wb + 1048576,     H_ * H_);
  cvt_kernel<<<512, 256, 0, stream>>>(vw, wb + 2097152,     H_ * H_);

  hipFuncSetAttribute((const void*)qkv_gemm,
                      hipFuncAttributeMaxDynamicSharedMemorySize, 131072);
  qkv_gemm<<<384, 512, 131072, stream>>>(actb, wb, qb, kb, vb, Qh, Kh, Vth);

  attn_kernel<<<1024, 256, 0, stream>>>(Qh, Kh, Vth, (float*)d_out);
}